// Round 6
// baseline (400.466 us; speedup 1.0000x reference)
//
#include <hip/hip_runtime.h>
#include <stdint.h>

typedef unsigned short u16;
typedef unsigned int   u32;
typedef __attribute__((ext_vector_type(8))) short short8;
typedef __attribute__((ext_vector_type(4))) float f32x4;

#define CHUNK 8192   // edges per block in hist/scatter phases

__device__ __forceinline__ u16 f2bf(float f) {
    u32 u = __float_as_uint(f);
    u32 r = (u + 0x7FFFu + ((u >> 16) & 1u)) >> 16;   // RNE
    return (u16)r;
}

// int64-stored-raw edge_index has every high 32-bit word zero (vals < 2^17).
__device__ __forceinline__ int edge_is64(const int* __restrict__ ei) {
    return ((ei[1] | ei[3] | ei[5] | ei[7] | ei[9] | ei[11]) == 0) ? 1 : 0;
}

__global__ void zero_out(float* __restrict__ p, size_t n) {
    size_t i = (size_t)blockIdx.x * 256 + threadIdx.x;
    size_t stride = (size_t)gridDim.x * 256;
    for (; i < n; i += stride) p[i] = 0.f;
}

// ---------------------------------------------------------------------------
// Phase 1: per-block histogram over coarse buckets (dst >> 8).
// cnt laid out bucket-major: cnt[B * nb + b]. No global atomics.
// ---------------------------------------------------------------------------
__global__ void hist_bucket(const int* __restrict__ ei, int* __restrict__ cnt,
                            int E, int N, int nb, int NBK) {
    __shared__ int h[256];
    int b = blockIdx.x, t = threadIdx.x;
    h[t] = 0;
    __syncthreads();
    int is64 = edge_is64(ei);
    int base = b * CHUNK;
    int endE = min(base + CHUNK, E);
    for (int i = base + t; i < endE; i += 256) {
        int dst = is64 ? ei[2 * E + 2 * i] : ei[E + i];
        dst = min(max(dst, 0), N - 1);
        atomicAdd(&h[dst >> 8], 1);
    }
    __syncthreads();
    for (int B = t; B < NBK; B += 256) cnt[B * nb + b] = h[B];
}

// ---------------------------------------------------------------------------
// Hierarchical exclusive scan (in place) over int array a[M].
// ---------------------------------------------------------------------------
__global__ void scan_partial(const int* __restrict__ a, int* __restrict__ bsum, int M) {
    __shared__ int sh[256];
    int t = threadIdx.x;
    int idx0 = blockIdx.x * 1024 + t * 4;
    int s = 0;
    #pragma unroll
    for (int i = 0; i < 4; ++i) { int idx = idx0 + i; if (idx < M) s += a[idx]; }
    sh[t] = s;
    __syncthreads();
    #pragma unroll
    for (int off = 128; off > 0; off >>= 1) {
        if (t < off) sh[t] += sh[t + off];
        __syncthreads();
    }
    if (t == 0) bsum[blockIdx.x] = sh[0];
}

__global__ void scan_bsum(int* __restrict__ bsum, int nbs) {
    __shared__ int sh[256];
    __shared__ int carry;
    int t = threadIdx.x;
    if (t == 0) carry = 0;
    __syncthreads();
    for (int base = 0; base < nbs; base += 256) {
        int v = (base + t < nbs) ? bsum[base + t] : 0;
        sh[t] = v;
        __syncthreads();
        #pragma unroll
        for (int off = 1; off < 256; off <<= 1) {
            int x = (t >= off) ? sh[t - off] : 0;
            __syncthreads();
            sh[t] += x;
            __syncthreads();
        }
        if (base + t < nbs) bsum[base + t] = carry + sh[t] - v;
        __syncthreads();
        if (t == 255) carry += sh[255];
        __syncthreads();
    }
}

__global__ void scan_final(int* __restrict__ a, const int* __restrict__ bsum, int M) {
    __shared__ int sh[256];
    int t = threadIdx.x;
    int idx0 = blockIdx.x * 1024 + t * 4;
    int v[4];
    int s = 0;
    #pragma unroll
    for (int i = 0; i < 4; ++i) {
        int idx = idx0 + i;
        v[i] = (idx < M) ? a[idx] : 0;
        s += v[i];
    }
    sh[t] = s;
    __syncthreads();
    #pragma unroll
    for (int off = 1; off < 256; off <<= 1) {
        int x = (t >= off) ? sh[t - off] : 0;
        __syncthreads();
        sh[t] += x;
        __syncthreads();
    }
    int run = sh[t] - s + bsum[blockIdx.x];
    #pragma unroll
    for (int i = 0; i < 4; ++i) {
        int idx = idx0 + i;
        if (idx < M) a[idx] = run;
        run += v[i];
    }
}

// ---------------------------------------------------------------------------
// Phase 3: scatter packed edges (src | (dst&255)<<17) into per-(block,bucket)
// exclusive regions. LDS cursors -> dense block-private global writes.
// ---------------------------------------------------------------------------
__global__ void scatter_pairs(const int* __restrict__ ei, const int* __restrict__ pboff,
                              u32* __restrict__ pairs, int E, int N, int nb, int NBK) {
    __shared__ int cur[256];
    int b = blockIdx.x, t = threadIdx.x;
    for (int B = t; B < NBK; B += 256) cur[B] = pboff[B * nb + b];
    __syncthreads();
    int is64 = edge_is64(ei);
    int base = b * CHUNK;
    int endE = min(base + CHUNK, E);
    for (int i = base + t; i < endE; i += 256) {
        int src = is64 ? ei[2 * i] : ei[i];
        int dst = is64 ? ei[2 * E + 2 * i] : ei[E + i];
        src = min(max(src, 0), N - 1);
        dst = min(max(dst, 0), N - 1);
        int slot = atomicAdd(&cur[dst >> 8], 1);
        pairs[slot] = (u32)src | ((u32)(dst & 255) << 17);
    }
}

// ---------------------------------------------------------------------------
// Phase 4: per-bucket counting sort (256 nodes). Writes offs[] and CSR ssrc.
// ---------------------------------------------------------------------------
__global__ void fine_sort(const u32* __restrict__ pairs, const int* __restrict__ pboff,
                          int* __restrict__ offs, int* __restrict__ ssrc,
                          int E, int N, int nb, int NBK) {
    __shared__ int hist[256];
    __shared__ int excl[256];
    __shared__ int cur[256];
    int B = blockIdx.x, t = threadIdx.x;
    if (B == 0 && t == 0) offs[N] = E;
    int rs = pboff[B * nb];
    int re = (B + 1 < NBK) ? pboff[(B + 1) * nb] : E;
    hist[t] = 0;
    __syncthreads();
    for (int i = rs + t; i < re; i += 256) {
        u32 p = pairs[i];
        atomicAdd(&hist[(p >> 17) & 255], 1);
    }
    __syncthreads();
    int v = hist[t];
    excl[t] = v;
    __syncthreads();
    #pragma unroll
    for (int off = 1; off < 256; off <<= 1) {
        int x = (t >= off) ? excl[t - off] : 0;
        __syncthreads();
        excl[t] += x;
        __syncthreads();
    }
    int ex = excl[t] - v;
    int node = B * 256 + t;
    if (node < N) offs[node] = rs + ex;
    cur[t] = rs + ex;
    __syncthreads();
    for (int i = rs + t; i < re; i += 256) {
        u32 p = pairs[i];
        int slot = atomicAdd(&cur[(p >> 17) & 255], 1);
        ssrc[slot] = (int)(p & 0x1FFFFu);
    }
}

// ---------------------------------------------------------------------------
// dtype prep: x -> bf16; all three weight pairs -> fused bf16 Wc in one launch.
// ---------------------------------------------------------------------------
__global__ void conv_bf16(const float4* __restrict__ x, uint2* __restrict__ H, int n4) {
    int i = blockIdx.x * 256 + threadIdx.x;
    if (i >= n4) return;
    float4 v = x[i];
    uint2 o;
    o.x = ((u32)f2bf(v.y) << 16) | f2bf(v.x);
    o.y = ((u32)f2bf(v.w) << 16) | f2bf(v.z);
    H[i] = o;
}

__global__ void prep_w_all(const float* __restrict__ Wl0, const float* __restrict__ Wr0,
                           const float* __restrict__ Wl1, const float* __restrict__ Wr1,
                           const float* __restrict__ Wl2, const float* __restrict__ Wr2,
                           u16* __restrict__ Wc0, u16* __restrict__ Wc1,
                           u16* __restrict__ Wc2) {
    int i = blockIdx.x * 256 + threadIdx.x;   // 0 .. 131071
    const float* Wl; const float* Wr; u16* Wc; int base;
    if (i < 32768)      { Wl = Wl0; Wr = Wr0; Wc = Wc0; base = i; }
    else if (i < 65536) { Wl = Wl1; Wr = Wr1; Wc = Wc1; base = i - 32768; }
    else                { Wl = Wl2; Wr = Wr2; Wc = Wc2; base = i - 65536; }
    int j = base >> 8, k = base & 255;
    float v = (k < 128) ? Wl[j * 128 + k] : Wr[j * 128 + (k - 128)];
    Wc[base] = f2bf(v);
}

// ---------------------------------------------------------------------------
// Mean-aggregate. Quarter-wave (16 lanes) per node, uint4 = 8 bf16 per lane.
// 4-way edge unroll. f32 accumulate, bf16 out.
// ---------------------------------------------------------------------------
__device__ __forceinline__ void acc8(float* a, uint4 p) {
    a[0] += __uint_as_float(p.x << 16); a[1] += __uint_as_float(p.x & 0xFFFF0000u);
    a[2] += __uint_as_float(p.y << 16); a[3] += __uint_as_float(p.y & 0xFFFF0000u);
    a[4] += __uint_as_float(p.z << 16); a[5] += __uint_as_float(p.z & 0xFFFF0000u);
    a[6] += __uint_as_float(p.w << 16); a[7] += __uint_as_float(p.w & 0xFFFF0000u);
}

__global__ void aggregate(const u16* __restrict__ H, const int* __restrict__ offs,
                          const int* __restrict__ ssrc, u16* __restrict__ M, int N) {
    int node = blockIdx.x * 16 + (threadIdx.x >> 4);
    int sub  = threadIdx.x & 15;
    if (node >= N) return;
    int beg = offs[node], end = offs[node + 1];
    float a0[8] = {}, a1[8] = {}, a2[8] = {}, a3[8] = {};
    int j = beg;
    for (; j + 3 < end; j += 4) {
        int s0 = ssrc[j], s1 = ssrc[j + 1], s2 = ssrc[j + 2], s3 = ssrc[j + 3];
        uint4 p0 = *(const uint4*)(H + (size_t)s0 * 128 + sub * 8);
        uint4 p1 = *(const uint4*)(H + (size_t)s1 * 128 + sub * 8);
        uint4 p2 = *(const uint4*)(H + (size_t)s2 * 128 + sub * 8);
        uint4 p3 = *(const uint4*)(H + (size_t)s3 * 128 + sub * 8);
        acc8(a0, p0); acc8(a1, p1); acc8(a2, p2); acc8(a3, p3);
    }
    for (; j < end; ++j) {
        uint4 p0 = *(const uint4*)(H + (size_t)ssrc[j] * 128 + sub * 8);
        acc8(a0, p0);
    }
    int d = end - beg;
    float sc = 1.f / (float)(d > 0 ? d : 1);
    #pragma unroll
    for (int i = 0; i < 8; ++i) a0[i] = (a0[i] + a1[i] + a2[i] + a3[i]) * sc;
    uint4 o;
    o.x = ((u32)f2bf(a0[1]) << 16) | f2bf(a0[0]);
    o.y = ((u32)f2bf(a0[3]) << 16) | f2bf(a0[2]);
    o.z = ((u32)f2bf(a0[5]) << 16) | f2bf(a0[4]);
    o.w = ((u32)f2bf(a0[7]) << 16) | f2bf(a0[6]);
    *(uint4*)(M + (size_t)node * 128 + sub * 8) = o;
}

// ---------------------------------------------------------------------------
// MFMA GEMM: out[i][j] = sum_k [M|H][i][k] * Wc[j][k] + bias[j] (+relu)
// Wave tile = 16 rows x 128 cols (acc = 8 f32x4 = 32 VGPRs); block = 4 waves
// = 64 rows. Doubles wave-parallelism vs round-5 (grid-starvation fix):
// layers 0/1 -> 3128 waves (12/CU), layer 2 -> 6256 (24/CU).
// ---------------------------------------------------------------------------
template<int DOUT, bool RELU, bool OUT_F32>
__global__ void gemm_mfma(const u16* __restrict__ M, const u16* __restrict__ H,
                          const u16* __restrict__ Wc, const float* __restrict__ bias,
                          void* __restrict__ out, int N) {
    int tid  = threadIdx.x;
    int w    = tid >> 6;
    int l    = tid & 63;
    int m_base = blockIdx.x * 64 + w * 16;
    int n_base = blockIdx.y * 128;

    int lr = l & 15;
    int lq = l >> 4;
    int kof = lq * 8;

    f32x4 acc[8];
    #pragma unroll
    for (int j = 0; j < 8; ++j) acc[j] = (f32x4){0.f, 0.f, 0.f, 0.f};

    int r0 = m_base + lr;
    const short8 zf = (short8){0,0,0,0,0,0,0,0};

    #pragma unroll
    for (int ks = 0; ks < 8; ++ks) {
        const u16* Asrc = (ks < 4) ? M : H;
        int ka = (ks & 3) * 32 + kof;
        short8 a0 = (r0 < N) ? *(const short8*)(Asrc + (size_t)r0 * 128 + ka) : zf;
        int kb = ks * 32 + kof;
        #pragma unroll
        for (int ct = 0; ct < 8; ++ct) {
            int wrow = n_base + ct * 16 + lr;
            short8 b = *(const short8*)(Wc + (size_t)wrow * 256 + kb);
            acc[ct] = __builtin_amdgcn_mfma_f32_16x16x32_bf16(a0, b, acc[ct], 0, 0, 0);
        }
    }

    #pragma unroll
    for (int ct = 0; ct < 8; ++ct) {
        int col = n_base + ct * 16 + lr;
        float bv = bias[col];
        #pragma unroll
        for (int i = 0; i < 4; ++i) {
            int row = m_base + lq * 4 + i;
            if (row >= N) continue;
            float v = acc[ct][i] + bv;
            if (RELU) v = fmaxf(v, 0.f);
            if (OUT_F32) ((float*)out)[(size_t)row * DOUT + col] = v;
            else         ((u16*)out)[(size_t)row * DOUT + col] = f2bf(v);
        }
    }
}

extern "C" void kernel_launch(void* const* d_in, const int* in_sizes, int n_in,
                              void* d_out, int out_size, void* d_ws, size_t ws_size,
                              hipStream_t stream) {
    const float* x   = (const float*)d_in[0];
    const int*   ei  = (const int*)d_in[1];
    const float* Wl0 = (const float*)d_in[2];
    const float* bl0 = (const float*)d_in[3];
    const float* Wr0 = (const float*)d_in[4];
    const float* Wl1 = (const float*)d_in[5];
    const float* bl1 = (const float*)d_in[6];
    const float* Wr1 = (const float*)d_in[7];
    const float* Wl2 = (const float*)d_in[8];
    const float* bl2 = (const float*)d_in[9];
    const float* Wr2 = (const float*)d_in[10];

    const int N = in_sizes[0] / 128;
    const int E = in_sizes[1] / 2;

    const int NBK = (N + 255) >> 8;
    const int nb  = (E + CHUNK - 1) / CHUNK;
    const int M_  = NBK * nb;
    const int nbs = (M_ + 1023) / 1024;

    size_t off = 0;
    auto alloc = [&](size_t bytes) -> size_t {
        size_t p = off;
        off += (bytes + 255) & ~(size_t)255;
        return p;
    };
    size_t o_cnt   = alloc((size_t)M_ * 4);
    size_t o_bsum  = alloc((size_t)nbs * 4);
    size_t o_offs  = alloc(((size_t)N + 1) * 4);
    size_t o_ssrc  = alloc((size_t)E * 4);
    size_t o_pairs = alloc((size_t)E * 4);
    size_t o_Hx    = alloc((size_t)N * 128 * 2);
    size_t o_Ha    = alloc((size_t)N * 128 * 2);
    size_t o_Hb    = alloc((size_t)N * 128 * 2);
    size_t o_Mb    = alloc((size_t)N * 128 * 2);
    size_t o_Wc0   = alloc((size_t)128 * 256 * 2);
    size_t o_Wc1   = alloc((size_t)128 * 256 * 2);
    size_t o_Wc2   = alloc((size_t)256 * 256 * 2);

    if (off > ws_size || NBK > 256 || N > (1 << 17)) {
        zero_out<<<2048, 256, 0, stream>>>((float*)d_out, (size_t)out_size);
        return;
    }

    char* ws = (char*)d_ws;
    int*  cnt   = (int*)(ws + o_cnt);
    int*  bsum  = (int*)(ws + o_bsum);
    int*  offs  = (int*)(ws + o_offs);
    int*  ssrc  = (int*)(ws + o_ssrc);
    u32*  pairs = (u32*)(ws + o_pairs);
    u16*  Hx    = (u16*)(ws + o_Hx);
    u16*  Ha    = (u16*)(ws + o_Ha);
    u16*  Hb    = (u16*)(ws + o_Hb);
    u16*  Mb    = (u16*)(ws + o_Mb);
    u16*  Wc0   = (u16*)(ws + o_Wc0);
    u16*  Wc1   = (u16*)(ws + o_Wc1);
    u16*  Wc2   = (u16*)(ws + o_Wc2);

    // CSR build: hist -> scan -> block-private scatter -> per-bucket sort
    hist_bucket<<<nb, 256, 0, stream>>>(ei, cnt, E, N, nb, NBK);
    scan_partial<<<nbs, 256, 0, stream>>>(cnt, bsum, M_);
    scan_bsum<<<1, 256, 0, stream>>>(bsum, nbs);
    scan_final<<<nbs, 256, 0, stream>>>(cnt, bsum, M_);
    scatter_pairs<<<nb, 256, 0, stream>>>(ei, cnt, pairs, E, N, nb, NBK);
    fine_sort<<<NBK, 256, 0, stream>>>(pairs, cnt, offs, ssrc, E, N, nb, NBK);

    // dtype prep
    int n4 = N * 32;
    conv_bf16<<<(n4 + 255) / 256, 256, 0, stream>>>((const float4*)x, (uint2*)Hx, n4);
    prep_w_all<<<512, 256, 0, stream>>>(Wl0, Wr0, Wl1, Wr1, Wl2, Wr2, Wc0, Wc1, Wc2);

    int ab = (N + 15) / 16;
    dim3 g1((N + 63) / 64, 1), g2((N + 63) / 64, 2);

    aggregate<<<ab, 256, 0, stream>>>(Hx, offs, ssrc, Mb, N);
    gemm_mfma<128, true, false><<<g1, 256, 0, stream>>>(Mb, Hx, Wc0, bl0, Ha, N);
    aggregate<<<ab, 256, 0, stream>>>(Ha, offs, ssrc, Mb, N);
    gemm_mfma<128, true, false><<<g1, 256, 0, stream>>>(Mb, Ha, Wc1, bl1, Hb, N);
    aggregate<<<ab, 256, 0, stream>>>(Hb, offs, ssrc, Mb, N);
    gemm_mfma<256, false, true><<<g2, 256, 0, stream>>>(Mb, Hb, Wc2, bl2, d_out, N);
}

// Round 7
// 354.277 us; speedup vs baseline: 1.1304x; 1.1304x over previous
//
#include <hip/hip_runtime.h>
#include <stdint.h>

typedef unsigned short u16;
typedef unsigned int   u32;
typedef __attribute__((ext_vector_type(8))) short short8;
typedef __attribute__((ext_vector_type(4))) float f32x4;

#define CHUNK 8192   // edges per block in hist/scatter phases

__device__ __forceinline__ u16 f2bf(float f) {
    u32 u = __float_as_uint(f);
    u32 r = (u + 0x7FFFu + ((u >> 16) & 1u)) >> 16;   // RNE
    return (u16)r;
}

// int64-stored-raw edge_index has every high 32-bit word zero (vals < 2^17).
__device__ __forceinline__ int edge_is64(const int* __restrict__ ei) {
    return ((ei[1] | ei[3] | ei[5] | ei[7] | ei[9] | ei[11]) == 0) ? 1 : 0;
}

__global__ void zero_out(float* __restrict__ p, size_t n) {
    size_t i = (size_t)blockIdx.x * 256 + threadIdx.x;
    size_t stride = (size_t)gridDim.x * 256;
    for (; i < n; i += stride) p[i] = 0.f;
}

// ---------------------------------------------------------------------------
// Phase 1: per-block histogram over coarse buckets (dst >> 8).
// ---------------------------------------------------------------------------
__global__ void hist_bucket(const int* __restrict__ ei, int* __restrict__ cnt,
                            int E, int N, int nb, int NBK) {
    __shared__ int h[256];
    int b = blockIdx.x, t = threadIdx.x;
    h[t] = 0;
    __syncthreads();
    int is64 = edge_is64(ei);
    int base = b * CHUNK;
    int endE = min(base + CHUNK, E);
    for (int i = base + t; i < endE; i += 256) {
        int dst = is64 ? ei[2 * E + 2 * i] : ei[E + i];
        dst = min(max(dst, 0), N - 1);
        atomicAdd(&h[dst >> 8], 1);
    }
    __syncthreads();
    for (int B = t; B < NBK; B += 256) cnt[B * nb + b] = h[B];
}

// ---------------------------------------------------------------------------
// Hierarchical exclusive scan (in place) over int array a[M].
// ---------------------------------------------------------------------------
__global__ void scan_partial(const int* __restrict__ a, int* __restrict__ bsum, int M) {
    __shared__ int sh[256];
    int t = threadIdx.x;
    int idx0 = blockIdx.x * 1024 + t * 4;
    int s = 0;
    #pragma unroll
    for (int i = 0; i < 4; ++i) { int idx = idx0 + i; if (idx < M) s += a[idx]; }
    sh[t] = s;
    __syncthreads();
    #pragma unroll
    for (int off = 128; off > 0; off >>= 1) {
        if (t < off) sh[t] += sh[t + off];
        __syncthreads();
    }
    if (t == 0) bsum[blockIdx.x] = sh[0];
}

__global__ void scan_bsum(int* __restrict__ bsum, int nbs) {
    __shared__ int sh[256];
    __shared__ int carry;
    int t = threadIdx.x;
    if (t == 0) carry = 0;
    __syncthreads();
    for (int base = 0; base < nbs; base += 256) {
        int v = (base + t < nbs) ? bsum[base + t] : 0;
        sh[t] = v;
        __syncthreads();
        #pragma unroll
        for (int off = 1; off < 256; off <<= 1) {
            int x = (t >= off) ? sh[t - off] : 0;
            __syncthreads();
            sh[t] += x;
            __syncthreads();
        }
        if (base + t < nbs) bsum[base + t] = carry + sh[t] - v;
        __syncthreads();
        if (t == 255) carry += sh[255];
        __syncthreads();
    }
}

__global__ void scan_final(int* __restrict__ a, const int* __restrict__ bsum, int M) {
    __shared__ int sh[256];
    int t = threadIdx.x;
    int idx0 = blockIdx.x * 1024 + t * 4;
    int v[4];
    int s = 0;
    #pragma unroll
    for (int i = 0; i < 4; ++i) {
        int idx = idx0 + i;
        v[i] = (idx < M) ? a[idx] : 0;
        s += v[i];
    }
    sh[t] = s;
    __syncthreads();
    #pragma unroll
    for (int off = 1; off < 256; off <<= 1) {
        int x = (t >= off) ? sh[t - off] : 0;
        __syncthreads();
        sh[t] += x;
        __syncthreads();
    }
    int run = sh[t] - s + bsum[blockIdx.x];
    #pragma unroll
    for (int i = 0; i < 4; ++i) {
        int idx = idx0 + i;
        if (idx < M) a[idx] = run;
        run += v[i];
    }
}

// ---------------------------------------------------------------------------
// Phase 3: scatter packed edges (src | (dst&255)<<17) into per-(block,bucket)
// exclusive regions. LDS cursors -> dense block-private global writes.
// ---------------------------------------------------------------------------
__global__ void scatter_pairs(const int* __restrict__ ei, const int* __restrict__ pboff,
                              u32* __restrict__ pairs, int E, int N, int nb, int NBK) {
    __shared__ int cur[256];
    int b = blockIdx.x, t = threadIdx.x;
    for (int B = t; B < NBK; B += 256) cur[B] = pboff[B * nb + b];
    __syncthreads();
    int is64 = edge_is64(ei);
    int base = b * CHUNK;
    int endE = min(base + CHUNK, E);
    for (int i = base + t; i < endE; i += 256) {
        int src = is64 ? ei[2 * i] : ei[i];
        int dst = is64 ? ei[2 * E + 2 * i] : ei[E + i];
        src = min(max(src, 0), N - 1);
        dst = min(max(dst, 0), N - 1);
        int slot = atomicAdd(&cur[dst >> 8], 1);
        pairs[slot] = (u32)src | ((u32)(dst & 255) << 17);
    }
}

// ---------------------------------------------------------------------------
// Phase 4: per-bucket counting sort (256 nodes). Writes offs[] and CSR ssrc.
// ---------------------------------------------------------------------------
__global__ void fine_sort(const u32* __restrict__ pairs, const int* __restrict__ pboff,
                          int* __restrict__ offs, int* __restrict__ ssrc,
                          int E, int N, int nb, int NBK) {
    __shared__ int hist[256];
    __shared__ int excl[256];
    __shared__ int cur[256];
    int B = blockIdx.x, t = threadIdx.x;
    if (B == 0 && t == 0) offs[N] = E;
    int rs = pboff[B * nb];
    int re = (B + 1 < NBK) ? pboff[(B + 1) * nb] : E;
    hist[t] = 0;
    __syncthreads();
    for (int i = rs + t; i < re; i += 256) {
        u32 p = pairs[i];
        atomicAdd(&hist[(p >> 17) & 255], 1);
    }
    __syncthreads();
    int v = hist[t];
    excl[t] = v;
    __syncthreads();
    #pragma unroll
    for (int off = 1; off < 256; off <<= 1) {
        int x = (t >= off) ? excl[t - off] : 0;
        __syncthreads();
        excl[t] += x;
        __syncthreads();
    }
    int ex = excl[t] - v;
    int node = B * 256 + t;
    if (node < N) offs[node] = rs + ex;
    cur[t] = rs + ex;
    __syncthreads();
    for (int i = rs + t; i < re; i += 256) {
        u32 p = pairs[i];
        int slot = atomicAdd(&cur[(p >> 17) & 255], 1);
        ssrc[slot] = (int)(p & 0x1FFFFu);
    }
}

// ---------------------------------------------------------------------------
// dtype prep
// ---------------------------------------------------------------------------
__global__ void conv_bf16(const float4* __restrict__ x, uint2* __restrict__ H, int n4) {
    int i = blockIdx.x * 256 + threadIdx.x;
    if (i >= n4) return;
    float4 v = x[i];
    uint2 o;
    o.x = ((u32)f2bf(v.y) << 16) | f2bf(v.x);
    o.y = ((u32)f2bf(v.w) << 16) | f2bf(v.z);
    H[i] = o;
}

__global__ void prep_w_all(const float* __restrict__ Wl0, const float* __restrict__ Wr0,
                           const float* __restrict__ Wl1, const float* __restrict__ Wr1,
                           const float* __restrict__ Wl2, const float* __restrict__ Wr2,
                           u16* __restrict__ Wc0, u16* __restrict__ Wc1,
                           u16* __restrict__ Wc2) {
    int i = blockIdx.x * 256 + threadIdx.x;   // 0 .. 131071
    const float* Wl; const float* Wr; u16* Wc; int base;
    if (i < 32768)      { Wl = Wl0; Wr = Wr0; Wc = Wc0; base = i; }
    else if (i < 65536) { Wl = Wl1; Wr = Wr1; Wc = Wc1; base = i - 32768; }
    else                { Wl = Wl2; Wr = Wr2; Wc = Wc2; base = i - 65536; }
    int j = base >> 8, k = base & 255;
    float v = (k < 128) ? Wl[j * 128 + k] : Wr[j * 128 + (k - 128)];
    Wc[base] = f2bf(v);
}

// ---------------------------------------------------------------------------
// Mean-aggregate. Quarter-wave (16 lanes) per node, uint4 = 8 bf16 per lane.
// ---------------------------------------------------------------------------
__device__ __forceinline__ void acc8(float* a, uint4 p) {
    a[0] += __uint_as_float(p.x << 16); a[1] += __uint_as_float(p.x & 0xFFFF0000u);
    a[2] += __uint_as_float(p.y << 16); a[3] += __uint_as_float(p.y & 0xFFFF0000u);
    a[4] += __uint_as_float(p.z << 16); a[5] += __uint_as_float(p.z & 0xFFFF0000u);
    a[6] += __uint_as_float(p.w << 16); a[7] += __uint_as_float(p.w & 0xFFFF0000u);
}

__global__ void aggregate(const u16* __restrict__ H, const int* __restrict__ offs,
                          const int* __restrict__ ssrc, u16* __restrict__ M, int N) {
    int node = blockIdx.x * 16 + (threadIdx.x >> 4);
    int sub  = threadIdx.x & 15;
    if (node >= N) return;
    int beg = offs[node], end = offs[node + 1];
    float a0[8] = {}, a1[8] = {}, a2[8] = {}, a3[8] = {};
    int j = beg;
    for (; j + 3 < end; j += 4) {
        int s0 = ssrc[j], s1 = ssrc[j + 1], s2 = ssrc[j + 2], s3 = ssrc[j + 3];
        uint4 p0 = *(const uint4*)(H + (size_t)s0 * 128 + sub * 8);
        uint4 p1 = *(const uint4*)(H + (size_t)s1 * 128 + sub * 8);
        uint4 p2 = *(const uint4*)(H + (size_t)s2 * 128 + sub * 8);
        uint4 p3 = *(const uint4*)(H + (size_t)s3 * 128 + sub * 8);
        acc8(a0, p0); acc8(a1, p1); acc8(a2, p2); acc8(a3, p3);
    }
    for (; j < end; ++j) {
        uint4 p0 = *(const uint4*)(H + (size_t)ssrc[j] * 128 + sub * 8);
        acc8(a0, p0);
    }
    int d = end - beg;
    float sc = 1.f / (float)(d > 0 ? d : 1);
    #pragma unroll
    for (int i = 0; i < 8; ++i) a0[i] = (a0[i] + a1[i] + a2[i] + a3[i]) * sc;
    uint4 o;
    o.x = ((u32)f2bf(a0[1]) << 16) | f2bf(a0[0]);
    o.y = ((u32)f2bf(a0[3]) << 16) | f2bf(a0[2]);
    o.z = ((u32)f2bf(a0[5]) << 16) | f2bf(a0[4]);
    o.w = ((u32)f2bf(a0[7]) << 16) | f2bf(a0[6]);
    *(uint4*)(M + (size_t)node * 128 + sub * 8) = o;
}

// ---------------------------------------------------------------------------
// MFMA GEMM: out[i][j] = sum_k [M|H][i][k] * Wc[j][k] + bias[j] (+relu)
// Wave tile = 32 rows x 128 cols (2 row-frags share every B load). ALL 16
// A-frags hoisted into registers up-front: 16 independent 16 B global loads
// = 16 KB in flight per wave (HBM saturation needs ~9.2 KB/CU).
// __launch_bounds__(256,3): ~170 VGPR cap = 64 A + 64 acc + B prefetch.
// ---------------------------------------------------------------------------
template<int DOUT, bool RELU, bool OUT_F32>
__global__ __launch_bounds__(256, 3)
void gemm_mfma(const u16* __restrict__ M, const u16* __restrict__ H,
               const u16* __restrict__ Wc, const float* __restrict__ bias,
               void* __restrict__ out, int N) {
    int tid  = threadIdx.x;
    int w    = tid >> 6;
    int l    = tid & 63;
    int m_base = blockIdx.x * 128 + w * 32;
    int n_base = blockIdx.y * 128;

    int lr = l & 15;
    int lq = l >> 4;
    int kof = lq * 8;

    int r0 = m_base + lr, r1 = r0 + 16;
    const short8 zf = (short8){0,0,0,0,0,0,0,0};

    // Hoist all A fragments: 16 independent global loads, issued back-to-back.
    short8 a[2][8];
    #pragma unroll
    for (int ks = 0; ks < 8; ++ks) {
        const u16* Asrc = (ks < 4) ? M : H;
        int ka = (ks & 3) * 32 + kof;
        a[0][ks] = (r0 < N) ? *(const short8*)(Asrc + (size_t)r0 * 128 + ka) : zf;
        a[1][ks] = (r1 < N) ? *(const short8*)(Asrc + (size_t)r1 * 128 + ka) : zf;
    }

    f32x4 acc[2][8];
    #pragma unroll
    for (int i = 0; i < 2; ++i)
        #pragma unroll
        for (int j = 0; j < 8; ++j) acc[i][j] = (f32x4){0.f, 0.f, 0.f, 0.f};

    #pragma unroll
    for (int ks = 0; ks < 8; ++ks) {
        int kb = ks * 32 + kof;
        #pragma unroll
        for (int ct = 0; ct < 8; ++ct) {
            int wrow = n_base + ct * 16 + lr;
            short8 b = *(const short8*)(Wc + (size_t)wrow * 256 + kb);
            acc[0][ct] = __builtin_amdgcn_mfma_f32_16x16x32_bf16(a[0][ks], b, acc[0][ct], 0, 0, 0);
            acc[1][ct] = __builtin_amdgcn_mfma_f32_16x16x32_bf16(a[1][ks], b, acc[1][ct], 0, 0, 0);
        }
    }

    #pragma unroll
    for (int rg = 0; rg < 2; ++rg) {
        #pragma unroll
        for (int ct = 0; ct < 8; ++ct) {
            int col = n_base + ct * 16 + lr;
            float bv = bias[col];
            #pragma unroll
            for (int i = 0; i < 4; ++i) {
                int row = m_base + rg * 16 + lq * 4 + i;
                if (row >= N) continue;
                float v = acc[rg][ct][i] + bv;
                if (RELU) v = fmaxf(v, 0.f);
                if (OUT_F32) ((float*)out)[(size_t)row * DOUT + col] = v;
                else         ((u16*)out)[(size_t)row * DOUT + col] = f2bf(v);
            }
        }
    }
}

extern "C" void kernel_launch(void* const* d_in, const int* in_sizes, int n_in,
                              void* d_out, int out_size, void* d_ws, size_t ws_size,
                              hipStream_t stream) {
    const float* x   = (const float*)d_in[0];
    const int*   ei  = (const int*)d_in[1];
    const float* Wl0 = (const float*)d_in[2];
    const float* bl0 = (const float*)d_in[3];
    const float* Wr0 = (const float*)d_in[4];
    const float* Wl1 = (const float*)d_in[5];
    const float* bl1 = (const float*)d_in[6];
    const float* Wr1 = (const float*)d_in[7];
    const float* Wl2 = (const float*)d_in[8];
    const float* bl2 = (const float*)d_in[9];
    const float* Wr2 = (const float*)d_in[10];

    const int N = in_sizes[0] / 128;
    const int E = in_sizes[1] / 2;

    const int NBK = (N + 255) >> 8;
    const int nb  = (E + CHUNK - 1) / CHUNK;
    const int M_  = NBK * nb;
    const int nbs = (M_ + 1023) / 1024;

    size_t off = 0;
    auto alloc = [&](size_t bytes) -> size_t {
        size_t p = off;
        off += (bytes + 255) & ~(size_t)255;
        return p;
    };
    size_t o_cnt   = alloc((size_t)M_ * 4);
    size_t o_bsum  = alloc((size_t)nbs * 4);
    size_t o_offs  = alloc(((size_t)N + 1) * 4);
    size_t o_ssrc  = alloc((size_t)E * 4);
    size_t o_pairs = alloc((size_t)E * 4);
    size_t o_Hx    = alloc((size_t)N * 128 * 2);
    size_t o_Ha    = alloc((size_t)N * 128 * 2);
    size_t o_Hb    = alloc((size_t)N * 128 * 2);
    size_t o_Mb    = alloc((size_t)N * 128 * 2);
    size_t o_Wc0   = alloc((size_t)128 * 256 * 2);
    size_t o_Wc1   = alloc((size_t)128 * 256 * 2);
    size_t o_Wc2   = alloc((size_t)256 * 256 * 2);

    if (off > ws_size || NBK > 256 || N > (1 << 17)) {
        zero_out<<<2048, 256, 0, stream>>>((float*)d_out, (size_t)out_size);
        return;
    }

    char* ws = (char*)d_ws;
    int*  cnt   = (int*)(ws + o_cnt);
    int*  bsum  = (int*)(ws + o_bsum);
    int*  offs  = (int*)(ws + o_offs);
    int*  ssrc  = (int*)(ws + o_ssrc);
    u32*  pairs = (u32*)(ws + o_pairs);
    u16*  Hx    = (u16*)(ws + o_Hx);
    u16*  Ha    = (u16*)(ws + o_Ha);
    u16*  Hb    = (u16*)(ws + o_Hb);
    u16*  Mb    = (u16*)(ws + o_Mb);
    u16*  Wc0   = (u16*)(ws + o_Wc0);
    u16*  Wc1   = (u16*)(ws + o_Wc1);
    u16*  Wc2   = (u16*)(ws + o_Wc2);

    // CSR build: hist -> scan -> block-private scatter -> per-bucket sort
    hist_bucket<<<nb, 256, 0, stream>>>(ei, cnt, E, N, nb, NBK);
    scan_partial<<<nbs, 256, 0, stream>>>(cnt, bsum, M_);
    scan_bsum<<<1, 256, 0, stream>>>(bsum, nbs);
    scan_final<<<nbs, 256, 0, stream>>>(cnt, bsum, M_);
    scatter_pairs<<<nb, 256, 0, stream>>>(ei, cnt, pairs, E, N, nb, NBK);
    fine_sort<<<NBK, 256, 0, stream>>>(pairs, cnt, offs, ssrc, E, N, nb, NBK);

    // dtype prep
    int n4 = N * 32;
    conv_bf16<<<(n4 + 255) / 256, 256, 0, stream>>>((const float4*)x, (uint2*)Hx, n4);
    prep_w_all<<<512, 256, 0, stream>>>(Wl0, Wr0, Wl1, Wr1, Wl2, Wr2, Wc0, Wc1, Wc2);

    int ab = (N + 15) / 16;
    dim3 g1((N + 127) / 128, 1), g2((N + 127) / 128, 2);

    aggregate<<<ab, 256, 0, stream>>>(Hx, offs, ssrc, Mb, N);
    gemm_mfma<128, true, false><<<g1, 256, 0, stream>>>(Mb, Hx, Wc0, bl0, Ha, N);
    aggregate<<<ab, 256, 0, stream>>>(Ha, offs, ssrc, Mb, N);
    gemm_mfma<128, true, false><<<g1, 256, 0, stream>>>(Mb, Ha, Wc1, bl1, Hb, N);
    aggregate<<<ab, 256, 0, stream>>>(Hb, offs, ssrc, Mb, N);
    gemm_mfma<256, false, true><<<g2, 256, 0, stream>>>(Mb, Hb, Wc2, bl2, d_out, N);
}